// Round 5
// baseline (165.038 us; speedup 1.0000x reference)
//
#include <hip/hip_runtime.h>
#include <hip/hip_bf16.h>

// Problem constants
#define Bn 32
#define Cn 32
#define Ln 512
#define INTRA 1024
#define INTER 256
#define DCP 64
#define DDE 512
#define SCALEF 0.05f

typedef __attribute__((ext_vector_type(8))) short short8;
typedef __attribute__((ext_vector_type(4))) float floatx4;

__device__ __forceinline__ short bf16_of(float f) {
    union { float f; unsigned u; } v; v.f = f;
    unsigned r = (v.u + 0x7FFFu + ((v.u >> 16) & 1u)) >> 16;
    return (short)r;
}
__device__ __forceinline__ float f_of_bf16(short h) {
    union { unsigned u; float f; } v;
    v.u = ((unsigned)(unsigned short)h) << 16;
    return v.f;
}

// ---------------------------------------------------------------------------
// Convert weights fp32 -> bf16 (layouts already [n][k] / [m][k] as needed).
// ---------------------------------------------------------------------------
__global__ __launch_bounds__(256) void prep_weights(
    const float* __restrict__ cW1, const float* __restrict__ cW2,
    const float* __restrict__ dW1, const float* __restrict__ dW2,
    short* __restrict__ cW1b, short* __restrict__ cW2b,
    short* __restrict__ dW1b, short* __restrict__ dW2b)
{
    int i = blockIdx.x * 256 + threadIdx.x;
    if (i < 64 * 256) cW1b[i] = bf16_of(cW1[i]);
    if (i < 64 * 64)  cW2b[i] = bf16_of(cW2[i]);
    if (i < DDE * INTRA) { dW1b[i] = bf16_of(dW1[i]); dW2b[i] = bf16_of(dW2[i]); }
}

// ---------------------------------------------------------------------------
// compress (barrier-free, LDS-free K-loop): each wave computes 16 rows.
//   T  = relu(tile @ cW1^T + cb1)   (16 x 64, wave-private)
//   M1 = T @ cW2^T + cb2            (16 x 64)
// A-frags read DIRECTLY from global (lane ln -> row m0+ln, k chunk quad*8),
// B-frags directly from cW1b/cW2b (row-major [n][k]).
// T transposed C-frag -> A-frag via tiny per-wave LDS scratch (one barrier).
// Output: M1T[c][d][i] bf16 (B-operand layout of denoise-1).
// ---------------------------------------------------------------------------
__global__ __launch_bounds__(256) void compress_fused(
    const float* __restrict__ map_raw, const short* __restrict__ cW1b,
    const float* __restrict__ cb1, const short* __restrict__ cW2b,
    const float* __restrict__ cb2, short* __restrict__ M1T)
{
    const int c    = blockIdx.y;
    const int t    = threadIdx.x;
    const int w    = t >> 6;
    const int lane = t & 63;
    const int ln   = lane & 15;
    const int quad = lane >> 4;
    const int m0   = blockIdx.x * 64 + w * 16;   // this wave's 16 rows

    const float* Ap = map_raw + ((long)c * INTRA + m0) * INTER + (long)ln * INTER + quad * 8;

    __shared__ short Ts[4][16 * 64];   // per-wave transpose scratch (8 KB)

    floatx4 acc[4] = {};

    // 2-deep prefetch buffers
    float4 pa0[2], pa1[2];
    short8 pb[2][4];
    #pragma unroll
    for (int ib = 0; ib < 2; ++ib) {
        const int kk = ib * 32;
        pa0[ib] = *(const float4*)(Ap + kk);
        pa1[ib] = *(const float4*)(Ap + kk + 4);
        #pragma unroll
        for (int nt = 0; nt < 4; ++nt)
            pb[ib][nt] = *(const short8*)(cW1b + (nt * 16 + ln) * INTER + kk + quad * 8);
    }

    int ib = 0;
    for (int k0 = 0; k0 < INTER; k0 += 32, ib ^= 1) {
        float4 c0 = pa0[ib], c1 = pa1[ib];
        short8 bc0 = pb[ib][0], bc1 = pb[ib][1], bc2 = pb[ib][2], bc3 = pb[ib][3];
        const int kn = k0 + 64;
        if (kn < INTER) {
            pa0[ib] = *(const float4*)(Ap + kn);
            pa1[ib] = *(const float4*)(Ap + kn + 4);
            #pragma unroll
            for (int nt = 0; nt < 4; ++nt)
                pb[ib][nt] = *(const short8*)(cW1b + (nt * 16 + ln) * INTER + kn + quad * 8);
        }
        short8 av;
        av[0] = bf16_of(c0.x); av[1] = bf16_of(c0.y);
        av[2] = bf16_of(c0.z); av[3] = bf16_of(c0.w);
        av[4] = bf16_of(c1.x); av[5] = bf16_of(c1.y);
        av[6] = bf16_of(c1.z); av[7] = bf16_of(c1.w);
        acc[0] = __builtin_amdgcn_mfma_f32_16x16x32_bf16(av, bc0, acc[0], 0, 0, 0);
        acc[1] = __builtin_amdgcn_mfma_f32_16x16x32_bf16(av, bc1, acc[1], 0, 0, 0);
        acc[2] = __builtin_amdgcn_mfma_f32_16x16x32_bf16(av, bc2, acc[2], 0, 0, 0);
        acc[3] = __builtin_amdgcn_mfma_f32_16x16x32_bf16(av, bc3, acc[3], 0, 0, 0);
    }

    // T = relu(acc + cb1), C-frag (row=quad*4+r, col=nt*16+ln) -> Ts[w][m][k]
    #pragma unroll
    for (int nt = 0; nt < 4; ++nt) {
        const int n = nt * 16 + ln;
        const float b = cb1[n];
        #pragma unroll
        for (int r = 0; r < 4; ++r)
            Ts[w][(quad * 4 + r) * 64 + n] = bf16_of(fmaxf(acc[nt][r] + b, 0.f));
    }
    __syncthreads();

    // Phase 2: M1 = T @ cW2^T + cb2.  A-frag from Ts, B-frag direct global.
    floatx4 acc2[4] = {};
    #pragma unroll
    for (int ks = 0; ks < 2; ++ks) {
        short8 af = *(const short8*)&Ts[w][ln * 64 + ks * 32 + quad * 8];
        #pragma unroll
        for (int nt = 0; nt < 4; ++nt) {
            short8 bf = *(const short8*)(cW2b + (nt * 16 + ln) * 64 + ks * 32 + quad * 8);
            acc2[nt] = __builtin_amdgcn_mfma_f32_16x16x32_bf16(af, bf, acc2[nt], 0, 0, 0);
        }
    }

    // store M1T[c][d][i]: d = nt*16+ln, i = m0 + quad*4 + r  (short4 along i)
    short* outp = M1T + (long)c * 64 * INTRA;
    #pragma unroll
    for (int nt = 0; nt < 4; ++nt) {
        const int n = nt * 16 + ln;
        const float b = cb2[n];
        short t0 = bf16_of(acc2[nt][0] + b);
        short t1 = bf16_of(acc2[nt][1] + b);
        short t2 = bf16_of(acc2[nt][2] + b);
        short t3 = bf16_of(acc2[nt][3] + b);
        *(short4*)(outp + (long)n * INTRA + m0 + quad * 4) = make_short4(t0, t1, t2, t3);
    }
}

// ---------------------------------------------------------------------------
// denoise-1 (LDS-free): HT[c][d][h] = relu(dW1 @ M1[c] + db1).
// Wave = 16 h-rows x 64 d-cols. A = dW1b [h][k] direct; B = M1T[c] [d][k] direct.
// ---------------------------------------------------------------------------
__global__ __launch_bounds__(256) void gemm_dn1(
    const short* __restrict__ dW1b, const short* __restrict__ M1T,
    const float* __restrict__ db1, short* __restrict__ HT)
{
    const int c    = blockIdx.y;
    const int t    = threadIdx.x;
    const int w    = t >> 6;
    const int lane = t & 63;
    const int ln   = lane & 15;
    const int quad = lane >> 4;
    const int h0   = (blockIdx.x * 4 + w) * 16;

    const short* Ap = dW1b + (long)(h0 + ln) * INTRA + quad * 8;
    const short* Bp = M1T + (long)c * 64 * INTRA + (long)ln * INTRA + quad * 8;

    floatx4 acc[4] = {};
    short8 pa[2];
    short8 pb[2][4];
    #pragma unroll
    for (int ib = 0; ib < 2; ++ib) {
        const int kk = ib * 32;
        pa[ib] = *(const short8*)(Ap + kk);
        #pragma unroll
        for (int nt = 0; nt < 4; ++nt)
            pb[ib][nt] = *(const short8*)(Bp + (long)nt * 16 * INTRA + kk);
    }

    int ib = 0;
    for (int k0 = 0; k0 < INTRA; k0 += 32, ib ^= 1) {
        short8 ac = pa[ib];
        short8 b0 = pb[ib][0], b1 = pb[ib][1], b2 = pb[ib][2], b3 = pb[ib][3];
        const int kn = k0 + 64;
        if (kn < INTRA) {
            pa[ib] = *(const short8*)(Ap + kn);
            #pragma unroll
            for (int nt = 0; nt < 4; ++nt)
                pb[ib][nt] = *(const short8*)(Bp + (long)nt * 16 * INTRA + kn);
        }
        acc[0] = __builtin_amdgcn_mfma_f32_16x16x32_bf16(ac, b0, acc[0], 0, 0, 0);
        acc[1] = __builtin_amdgcn_mfma_f32_16x16x32_bf16(ac, b1, acc[1], 0, 0, 0);
        acc[2] = __builtin_amdgcn_mfma_f32_16x16x32_bf16(ac, b2, acc[2], 0, 0, 0);
        acc[3] = __builtin_amdgcn_mfma_f32_16x16x32_bf16(ac, b3, acc[3], 0, 0, 0);
    }

    float bm[4];
    #pragma unroll
    for (int r = 0; r < 4; ++r) bm[r] = db1[h0 + quad * 4 + r];

    // store HT[c][d][h]: d = nt*16+ln, h = h0 + quad*4 + r (short4 along h)
    short* outp = HT + (long)c * 64 * DDE;
    #pragma unroll
    for (int nt = 0; nt < 4; ++nt) {
        const int d = nt * 16 + ln;
        float v0 = fmaxf(acc[nt][0] + bm[0], 0.f);
        float v1 = fmaxf(acc[nt][1] + bm[1], 0.f);
        float v2 = fmaxf(acc[nt][2] + bm[2], 0.f);
        float v3 = fmaxf(acc[nt][3] + bm[3], 0.f);
        *(short4*)(outp + (long)d * DDE + h0 + quad * 4) =
            make_short4(bf16_of(v0), bf16_of(v1), bf16_of(v2), bf16_of(v3));
    }
}

// ---------------------------------------------------------------------------
// denoise-2 (LDS-free): S[c][i][d] = dW2 @ H[c] + db2, m=d, n=i.
// Wave = one d-tile (16) x 8 i-tiles (128 i). A = HT[c][d][k]; B = dW2b [i][k].
// ---------------------------------------------------------------------------
__global__ __launch_bounds__(256) void gemm_dn2(
    const short* __restrict__ HT, const short* __restrict__ dW2b,
    const float* __restrict__ db2, short* __restrict__ S16)
{
    const int c    = blockIdx.y;
    const int t    = threadIdx.x;
    const int w    = t >> 6;
    const int lane = t & 63;
    const int ln   = lane & 15;
    const int quad = lane >> 4;
    const int widx = blockIdx.x * 4 + w;       // 0..31
    const int dt   = widx & 3;                 // d-tile
    const int i0   = (widx >> 2) * 128;        // i-group base

    const short* Ap = HT + (long)c * 64 * DDE + (long)(dt * 16 + ln) * DDE + quad * 8;
    const short* Bp = dW2b + (long)i0 * DDE + (long)ln * DDE + quad * 8;

    floatx4 acc[8] = {};
    short8 pa[2];
    short8 pb[2][8];
    #pragma unroll
    for (int ib = 0; ib < 2; ++ib) {
        const int kk = ib * 32;
        pa[ib] = *(const short8*)(Ap + kk);
        #pragma unroll
        for (int nt = 0; nt < 8; ++nt)
            pb[ib][nt] = *(const short8*)(Bp + (long)nt * 16 * DDE + kk);
    }

    int ib = 0;
    for (int k0 = 0; k0 < DDE; k0 += 32, ib ^= 1) {
        short8 ac = pa[ib];
        short8 bc[8];
        #pragma unroll
        for (int nt = 0; nt < 8; ++nt) bc[nt] = pb[ib][nt];
        const int kn = k0 + 64;
        if (kn < DDE) {
            pa[ib] = *(const short8*)(Ap + kn);
            #pragma unroll
            for (int nt = 0; nt < 8; ++nt)
                pb[ib][nt] = *(const short8*)(Bp + (long)nt * 16 * DDE + kn);
        }
        #pragma unroll
        for (int nt = 0; nt < 8; ++nt)
            acc[nt] = __builtin_amdgcn_mfma_f32_16x16x32_bf16(ac, bc[nt], acc[nt], 0, 0, 0);
    }

    // store: C[row=d][col=i]; d = dt*16 + quad*4 + r, i = i0 + nt*16 + ln
    const int d0 = dt * 16 + quad * 4;
    #pragma unroll
    for (int nt = 0; nt < 8; ++nt) {
        const int i = i0 + nt * 16 + ln;
        const float bb = db2[i];
        short t0 = bf16_of(acc[nt][0] + bb);
        short t1 = bf16_of(acc[nt][1] + bb);
        short t2 = bf16_of(acc[nt][2] + bb);
        short t3 = bf16_of(acc[nt][3] + bb);
        *(short4*)(S16 + ((long)c * INTRA + i) * DCP + d0) = make_short4(t0, t1, t2, t3);
    }
}

// ---------------------------------------------------------------------------
// Fused gather + L1-score + softmax + weighted-sum + blend (round-4, passing).
// ---------------------------------------------------------------------------
__global__ __launch_bounds__(256) void fuse_kernel(
    const float* __restrict__ x_loc, const int* __restrict__ indices,
    const short* __restrict__ S16, const float* __restrict__ lamda1,
    const float* __restrict__ lamda2, float* __restrict__ out)
{
    const int c = blockIdx.x;
    const int b = blockIdx.y;

    __shared__ float xs[Ln];
    __shared__ int   idx[Ln];
    __shared__ float red[4][DCP];
    __shared__ short wbf[DCP];
    __shared__ float ob[Ln];

    const int t = threadIdx.x;
    const float* xp = x_loc + ((long)b * Cn + c) * Ln;
    const int*   ip = indices + (long)b * Ln;
    ((float2*)xs)[t] = ((const float2*)xp)[t];
    ((int2*)idx)[t]  = ((const int2*)ip)[t];
    __syncthreads();

    const short* Sc = S16 + (long)c * INTRA * DCP;
    const int lane = t & 63;
    const int w    = t >> 6;
    const int r    = lane >> 4;    // row-in-group 0..3
    const int dg   = lane & 15;    // d-group: d = dg*4..dg*4+3

    // Phase 1: scores[d] = sum_l |x[l] - S[c][idx[l]][d]|
    float s0 = 0.f, s1 = 0.f, s2 = 0.f, s3 = 0.f;
    #pragma unroll 4
    for (int i = 0; i < 32; ++i) {
        const int lbase = w * 128 + i * 4;
        const int row   = idx[lbase + r];
        short4 g = *(const short4*)(Sc + (long)row * DCP + dg * 4);
        const float x = xs[lbase + r];
        s0 += fabsf(x - f_of_bf16(g.x));
        s1 += fabsf(x - f_of_bf16(g.y));
        s2 += fabsf(x - f_of_bf16(g.z));
        s3 += fabsf(x - f_of_bf16(g.w));
    }
    s0 += __shfl_xor(s0, 16); s0 += __shfl_xor(s0, 32);
    s1 += __shfl_xor(s1, 16); s1 += __shfl_xor(s1, 32);
    s2 += __shfl_xor(s2, 16); s2 += __shfl_xor(s2, 32);
    s3 += __shfl_xor(s3, 16); s3 += __shfl_xor(s3, 32);
    if (lane < 16) {
        red[w][dg * 4 + 0] = s0;
        red[w][dg * 4 + 1] = s1;
        red[w][dg * 4 + 2] = s2;
        red[w][dg * 4 + 3] = s3;
    }
    __syncthreads();

    // Softmax over d (wave 0)
    if (t < DCP) {
        float sc = red[0][t] + red[1][t] + red[2][t] + red[3][t];
        sc = -sc * (SCALEF * 0.044194173824159216f);  // * 1/sqrt(512)
        float m = sc;
        #pragma unroll
        for (int o = 32; o > 0; o >>= 1) m = fmaxf(m, __shfl_xor(m, o));
        float e = __expf(sc - m);
        float ssum = e;
        #pragma unroll
        for (int o = 32; o > 0; o >>= 1) ssum += __shfl_xor(ssum, o);
        wbf[t] = bf16_of(e / ssum);
    }
    __syncthreads();

    // Phase 2: out[l] = sum_d w[d] * G[l][d] via MFMA matvec.
    const int quad = lane >> 4;
    const int ln16 = lane & 15;
    short8 bw0 = *(const short8*)&wbf[quad * 8];
    short8 bw1 = *(const short8*)&wbf[32 + quad * 8];

    #pragma unroll
    for (int mt = 0; mt < 8; ++mt) {
        const int mrow = w * 128 + mt * 16 + ln16;   // l (A-frag m index)
        const short* rp = Sc + (long)idx[mrow] * DCP;
        short8 a0 = *(const short8*)(rp + quad * 8);
        short8 a1 = *(const short8*)(rp + 32 + quad * 8);
        floatx4 acc = {};
        acc = __builtin_amdgcn_mfma_f32_16x16x32_bf16(a0, bw0, acc, 0, 0, 0);
        acc = __builtin_amdgcn_mfma_f32_16x16x32_bf16(a1, bw1, acc, 0, 0, 0);
        if (ln16 == 0) {   // C col n=0 lives in lanes 0,16,32,48; row = quad*4+r'
            const int l0 = w * 128 + mt * 16 + quad * 4;
            ob[l0 + 0] = acc[0];
            ob[l0 + 1] = acc[1];
            ob[l0 + 2] = acc[2];
            ob[l0 + 3] = acc[3];
        }
    }
    __syncthreads();

    // Final blend, coalesced
    const float lam1 = 1.f / (1.f + __expf(-lamda1[c]));
    #pragma unroll
    for (int j = 0; j < 2; ++j) {
        const int l = t + j * 256;
        const float lam = lam1 * (1.f / (1.f + __expf(-lamda2[l])));
        out[((long)b * Cn + c) * Ln + l] = ob[l] * lam + xs[l] * (1.f - lam);
    }
}

// ---------------------------------------------------------------------------
// Launch
// ---------------------------------------------------------------------------
extern "C" void kernel_launch(void* const* d_in, const int* in_sizes, int n_in,
                              void* d_out, int out_size, void* d_ws, size_t ws_size,
                              hipStream_t stream)
{
    const float* x_loc   = (const float*)d_in[0];
    const int*   indices = (const int*)d_in[1];
    const float* map_raw = (const float*)d_in[2];
    const float* cW1     = (const float*)d_in[3];
    const float* cb1     = (const float*)d_in[4];
    const float* cW2     = (const float*)d_in[5];
    const float* cb2     = (const float*)d_in[6];
    const float* dW1     = (const float*)d_in[7];
    const float* db1     = (const float*)d_in[8];
    const float* dW2     = (const float*)d_in[9];
    const float* db2     = (const float*)d_in[10];
    const float* lamda1  = (const float*)d_in[11];
    const float* lamda2  = (const float*)d_in[12];
    float* out = (float*)d_out;

    short* wsS  = (short*)d_ws;
    short* cW1b = wsS;                       // 64*256   = 16384
    short* cW2b = cW1b + 16384;              // 64*64    = 4096
    short* dW1b = cW2b + 4096;               // 512*1024 = 524288
    short* dW2b = dW1b + 524288;             // 1024*512 = 524288
    short* M1T  = dW2b + 524288;             // 32*64*1024 = 2097152
    short* HT   = M1T + 2097152;             // 32*64*512  = 1048576
    short* S16  = HT + 1048576;              // 32*1024*64 = 2097152

    prep_weights<<<2048, 256, 0, stream>>>(cW1, cW2, dW1, dW2,
                                           cW1b, cW2b, dW1b, dW2b);

    compress_fused<<<dim3(INTRA / 64, Cn), 256, 0, stream>>>(
        map_raw, cW1b, cb1, cW2b, cb2, M1T);

    gemm_dn1<<<dim3(DDE / 64, Cn), 256, 0, stream>>>(
        dW1b, M1T, db1, HT);

    gemm_dn2<<<dim3(INTRA / 64 / 4, Cn), 256, 0, stream>>>(
        HT, dW2b, db2, S16);

    fuse_kernel<<<dim3(Cn, Bn), 256, 0, stream>>>(
        x_loc, indices, S16, lamda1, lamda2, out);
}

// Round 6
// 144.760 us; speedup vs baseline: 1.1401x; 1.1401x over previous
//
#include <hip/hip_runtime.h>
#include <hip/hip_bf16.h>

// Problem constants
#define Bn 32
#define Cn 32
#define Ln 512
#define INTRA 1024
#define INTER 256
#define DCP 64
#define DDE 512
#define SCALEF 0.05f

typedef __attribute__((ext_vector_type(8))) short short8;
typedef __attribute__((ext_vector_type(4))) float floatx4;

__device__ __forceinline__ short bf16_of(float f) {
    union { float f; unsigned u; } v; v.f = f;
    unsigned r = (v.u + 0x7FFFu + ((v.u >> 16) & 1u)) >> 16;
    return (short)r;
}
__device__ __forceinline__ float f_of_bf16(short h) {
    union { unsigned u; float f; } v;
    v.u = ((unsigned)(unsigned short)h) << 16;
    return v.f;
}
__device__ __forceinline__ short8 cvt8(float4 a, float4 b) {
    short8 r;
    r[0] = bf16_of(a.x); r[1] = bf16_of(a.y); r[2] = bf16_of(a.z); r[3] = bf16_of(a.w);
    r[4] = bf16_of(b.x); r[5] = bf16_of(b.y); r[6] = bf16_of(b.z); r[7] = bf16_of(b.w);
    return r;
}

// ---------------------------------------------------------------------------
// compress: T = relu(tile @ cW1^T + cb1); M1 = T @ cW2^T + cb2.
// fp32 weights converted in-staging (no prep kernel). BK=64 -> 4 iterations.
// Output M1T[c][d][i] bf16 (B-operand layout of denoise-1).
// Grid (16, 32) = 512 blocks, 256 thr. LDS 27.6 KB.
// ---------------------------------------------------------------------------
__global__ __launch_bounds__(256) void compress_fused(
    const float* __restrict__ map_raw, const float* __restrict__ cW1,
    const float* __restrict__ cb1, const float* __restrict__ cW2,
    const float* __restrict__ cb2, short* __restrict__ M1T)
{
    const int c  = blockIdx.y;
    const int m0 = blockIdx.x * 64;
    const float* A = map_raw + ((long)c * INTRA + m0) * INTER;

    __shared__ short Asb[64 * 72];   // bf16 A-tile [m][k], stride 72
    __shared__ short Bsb[64 * 72];   // bf16 cW1-tile [n][k]
    __shared__ short Tsb[64 * 72];   // T [m][e], stride 72

    const int t = threadIdx.x, w = t >> 6, lane = t & 63;
    const int ln = lane & 15, quad = lane >> 4;
    const int sr = t >> 2, sk = (t & 3) * 16;   // staging: 64 rows, 16 els/thread

    const float* ap = A + sr * INTER + sk;
    const float* bp = cW1 + sr * INTER + sk;

    floatx4 acc[4] = {};
    float4 a0 = *(const float4*)(ap),     a1 = *(const float4*)(ap + 4);
    float4 a2 = *(const float4*)(ap + 8), a3 = *(const float4*)(ap + 12);
    float4 b0 = *(const float4*)(bp),     b1 = *(const float4*)(bp + 4);
    float4 b2 = *(const float4*)(bp + 8), b3 = *(const float4*)(bp + 12);

    for (int k0 = 0; k0 < INTER; k0 += 64) {
        __syncthreads();
        *(short8*)&Asb[sr * 72 + sk]     = cvt8(a0, a1);
        *(short8*)&Asb[sr * 72 + sk + 8] = cvt8(a2, a3);
        *(short8*)&Bsb[sr * 72 + sk]     = cvt8(b0, b1);
        *(short8*)&Bsb[sr * 72 + sk + 8] = cvt8(b2, b3);
        __syncthreads();
        const int kn = k0 + 64;
        if (kn < INTER) {
            a0 = *(const float4*)(ap + kn);     a1 = *(const float4*)(ap + kn + 4);
            a2 = *(const float4*)(ap + kn + 8); a3 = *(const float4*)(ap + kn + 12);
            b0 = *(const float4*)(bp + kn);     b1 = *(const float4*)(bp + kn + 4);
            b2 = *(const float4*)(bp + kn + 8); b3 = *(const float4*)(bp + kn + 12);
        }
        #pragma unroll
        for (int kc = 0; kc < 2; ++kc) {
            short8 af = *(const short8*)&Asb[(w * 16 + ln) * 72 + kc * 32 + quad * 8];
            #pragma unroll
            for (int nt = 0; nt < 4; ++nt) {
                short8 bf = *(const short8*)&Bsb[(nt * 16 + ln) * 72 + kc * 32 + quad * 8];
                acc[nt] = __builtin_amdgcn_mfma_f32_16x16x32_bf16(af, bf, acc[nt], 0, 0, 0);
            }
        }
    }
    __syncthreads();

    // T = relu(acc + cb1) -> Tsb[m][e]
    #pragma unroll
    for (int nt = 0; nt < 4; ++nt) {
        const int n = nt * 16 + ln;
        const float b = cb1[n];
        #pragma unroll
        for (int r = 0; r < 4; ++r)
            Tsb[(w * 16 + quad * 4 + r) * 72 + n] = bf16_of(fmaxf(acc[nt][r] + b, 0.f));
    }
    __syncthreads();

    // Phase 2: M1 = T @ cW2^T + cb2. B-frags: fp32 cW2 direct from global, cvt.
    floatx4 acc2[4] = {};
    #pragma unroll
    for (int ks = 0; ks < 2; ++ks) {
        short8 af = *(const short8*)&Tsb[(w * 16 + ln) * 72 + ks * 32 + quad * 8];
        #pragma unroll
        for (int nt = 0; nt < 4; ++nt) {
            const float* wp = cW2 + (nt * 16 + ln) * 64 + ks * 32 + quad * 8;
            short8 bf = cvt8(*(const float4*)wp, *(const float4*)(wp + 4));
            acc2[nt] = __builtin_amdgcn_mfma_f32_16x16x32_bf16(af, bf, acc2[nt], 0, 0, 0);
        }
    }

    // store M1T[c][d][i]: d = nt*16+ln, i = m0 + w*16 + quad*4 + r
    short* outp = M1T + (long)c * 64 * INTRA;
    #pragma unroll
    for (int nt = 0; nt < 4; ++nt) {
        const int n = nt * 16 + ln;
        const float b = cb2[n];
        short t0 = bf16_of(acc2[nt][0] + b);
        short t1 = bf16_of(acc2[nt][1] + b);
        short t2 = bf16_of(acc2[nt][2] + b);
        short t3 = bf16_of(acc2[nt][3] + b);
        *(short4*)(outp + (long)n * INTRA + m0 + w * 16 + quad * 4) =
            make_short4(t0, t1, t2, t3);
    }
}

// ---------------------------------------------------------------------------
// denoise-1: HT[c][d][h] = relu(dW1 @ M1[c] + db1). Tile 32(h) x 64(d), BK=128.
// Grid (16, 32) = 512 blocks -> 2 blocks/CU. LDS 26 KB. dW1 fp32 cvt in-staging.
// Wave w: m-tile (w&1), n-tiles (w>>1)*2 + {0,1}.
// ---------------------------------------------------------------------------
__global__ __launch_bounds__(256) void gemm_dn1(
    const float* __restrict__ dW1, const short* __restrict__ M1T,
    const float* __restrict__ db1, short* __restrict__ HT)
{
    const int c  = blockIdx.y;
    const int h0 = blockIdx.x * 32;

    __shared__ short Asb[32 * 136];
    __shared__ short Bsb[64 * 136];

    const int t = threadIdx.x, w = t >> 6, lane = t & 63;
    const int ln = lane & 15, quad = lane >> 4;
    const int ar = t >> 3, ak = (t & 7) * 16;   // A staging: 32 rows, 16 floats
    const int br = t >> 2, bk = (t & 3) * 32;   // B staging: 64 rows, 32 shorts

    const float* Ap = dW1 + (long)(h0 + ar) * INTRA + ak;
    const short* Bp = M1T + (long)c * 64 * INTRA + (long)br * INTRA + bk;

    floatx4 acc[2] = {};
    float4 fa0 = *(const float4*)(Ap),     fa1 = *(const float4*)(Ap + 4);
    float4 fa2 = *(const float4*)(Ap + 8), fa3 = *(const float4*)(Ap + 12);
    short8 sb0 = *(const short8*)(Bp),      sb1 = *(const short8*)(Bp + 8);
    short8 sb2 = *(const short8*)(Bp + 16), sb3 = *(const short8*)(Bp + 24);

    const int mb = (w & 1) * 16;
    const int nb = (w >> 1) * 2;

    for (int k0 = 0; k0 < INTRA; k0 += 128) {
        __syncthreads();
        *(short8*)&Asb[ar * 136 + ak]      = cvt8(fa0, fa1);
        *(short8*)&Asb[ar * 136 + ak + 8]  = cvt8(fa2, fa3);
        *(short8*)&Bsb[br * 136 + bk]      = sb0;
        *(short8*)&Bsb[br * 136 + bk + 8]  = sb1;
        *(short8*)&Bsb[br * 136 + bk + 16] = sb2;
        *(short8*)&Bsb[br * 136 + bk + 24] = sb3;
        __syncthreads();
        const int kn = k0 + 128;
        if (kn < INTRA) {
            fa0 = *(const float4*)(Ap + kn);     fa1 = *(const float4*)(Ap + kn + 4);
            fa2 = *(const float4*)(Ap + kn + 8); fa3 = *(const float4*)(Ap + kn + 12);
            sb0 = *(const short8*)(Bp + kn);      sb1 = *(const short8*)(Bp + kn + 8);
            sb2 = *(const short8*)(Bp + kn + 16); sb3 = *(const short8*)(Bp + kn + 24);
        }
        #pragma unroll
        for (int kc = 0; kc < 4; ++kc) {
            short8 af  = *(const short8*)&Asb[(mb + ln) * 136 + kc * 32 + quad * 8];
            short8 bf0 = *(const short8*)&Bsb[((nb + 0) * 16 + ln) * 136 + kc * 32 + quad * 8];
            short8 bf1 = *(const short8*)&Bsb[((nb + 1) * 16 + ln) * 136 + kc * 32 + quad * 8];
            acc[0] = __builtin_amdgcn_mfma_f32_16x16x32_bf16(af, bf0, acc[0], 0, 0, 0);
            acc[1] = __builtin_amdgcn_mfma_f32_16x16x32_bf16(af, bf1, acc[1], 0, 0, 0);
        }
    }

    float bm[4];
    #pragma unroll
    for (int r = 0; r < 4; ++r) bm[r] = db1[h0 + mb + quad * 4 + r];

    short* outp = HT + (long)c * 64 * DDE;
    #pragma unroll
    for (int j = 0; j < 2; ++j) {
        const int d = (nb + j) * 16 + ln;
        float v0 = fmaxf(acc[j][0] + bm[0], 0.f);
        float v1 = fmaxf(acc[j][1] + bm[1], 0.f);
        float v2 = fmaxf(acc[j][2] + bm[2], 0.f);
        float v3 = fmaxf(acc[j][3] + bm[3], 0.f);
        *(short4*)(outp + (long)d * DDE + h0 + mb + quad * 4) =
            make_short4(bf16_of(v0), bf16_of(v1), bf16_of(v2), bf16_of(v3));
    }
}

// ---------------------------------------------------------------------------
// denoise-2: S[c][i][d] = dW2 @ H[c] + db2  (m=d 64, n=i tiles of 64), BK=128.
// Grid (16, 32) = 512 blocks. LDS 34.8 KB. dW2 fp32 cvt in-staging.
// ---------------------------------------------------------------------------
__global__ __launch_bounds__(256) void gemm_dn2(
    const short* __restrict__ HT, const float* __restrict__ dW2,
    const float* __restrict__ db2, short* __restrict__ S16)
{
    const int c  = blockIdx.y;
    const int n0 = blockIdx.x * 64;

    __shared__ short Asb[64 * 136];
    __shared__ short Bsb[64 * 136];

    const int t = threadIdx.x, w = t >> 6, lane = t & 63;
    const int ln = lane & 15, quad = lane >> 4;
    const int ar = t >> 2, ak = (t & 3) * 32;   // 64 rows, 32 els/thread

    const short* Ap = HT + (long)c * 64 * DDE + (long)ar * DDE + ak;
    const float* Bp = dW2 + (long)(n0 + ar) * DDE + ak;

    floatx4 acc[4] = {};
    short8 sa0 = *(const short8*)(Ap),      sa1 = *(const short8*)(Ap + 8);
    short8 sa2 = *(const short8*)(Ap + 16), sa3 = *(const short8*)(Ap + 24);
    float4 fb0 = *(const float4*)(Bp),      fb1 = *(const float4*)(Bp + 4);
    float4 fb2 = *(const float4*)(Bp + 8),  fb3 = *(const float4*)(Bp + 12);
    float4 fb4 = *(const float4*)(Bp + 16), fb5 = *(const float4*)(Bp + 20);
    float4 fb6 = *(const float4*)(Bp + 24), fb7 = *(const float4*)(Bp + 28);

    for (int k0 = 0; k0 < DDE; k0 += 128) {
        __syncthreads();
        *(short8*)&Asb[ar * 136 + ak]      = sa0;
        *(short8*)&Asb[ar * 136 + ak + 8]  = sa1;
        *(short8*)&Asb[ar * 136 + ak + 16] = sa2;
        *(short8*)&Asb[ar * 136 + ak + 24] = sa3;
        *(short8*)&Bsb[ar * 136 + ak]      = cvt8(fb0, fb1);
        *(short8*)&Bsb[ar * 136 + ak + 8]  = cvt8(fb2, fb3);
        *(short8*)&Bsb[ar * 136 + ak + 16] = cvt8(fb4, fb5);
        *(short8*)&Bsb[ar * 136 + ak + 24] = cvt8(fb6, fb7);
        __syncthreads();
        const int kn = k0 + 128;
        if (kn < DDE) {
            sa0 = *(const short8*)(Ap + kn);      sa1 = *(const short8*)(Ap + kn + 8);
            sa2 = *(const short8*)(Ap + kn + 16); sa3 = *(const short8*)(Ap + kn + 24);
            fb0 = *(const float4*)(Bp + kn);      fb1 = *(const float4*)(Bp + kn + 4);
            fb2 = *(const float4*)(Bp + kn + 8);  fb3 = *(const float4*)(Bp + kn + 12);
            fb4 = *(const float4*)(Bp + kn + 16); fb5 = *(const float4*)(Bp + kn + 20);
            fb6 = *(const float4*)(Bp + kn + 24); fb7 = *(const float4*)(Bp + kn + 28);
        }
        #pragma unroll
        for (int kc = 0; kc < 4; ++kc) {
            short8 af = *(const short8*)&Asb[(w * 16 + ln) * 136 + kc * 32 + quad * 8];
            #pragma unroll
            for (int nt = 0; nt < 4; ++nt) {
                short8 bf = *(const short8*)&Bsb[(nt * 16 + ln) * 136 + kc * 32 + quad * 8];
                acc[nt] = __builtin_amdgcn_mfma_f32_16x16x32_bf16(af, bf, acc[nt], 0, 0, 0);
            }
        }
    }

    // C[m=d][n=i]; d = w*16 + quad*4 + r, i = n0 + nt*16 + ln
    const int d0 = w * 16 + quad * 4;
    #pragma unroll
    for (int nt = 0; nt < 4; ++nt) {
        const int i = n0 + nt * 16 + ln;
        const float bb = db2[i];
        short t0 = bf16_of(acc[nt][0] + bb);
        short t1 = bf16_of(acc[nt][1] + bb);
        short t2 = bf16_of(acc[nt][2] + bb);
        short t3 = bf16_of(acc[nt][3] + bb);
        *(short4*)(S16 + ((long)c * INTRA + i) * DCP + d0) = make_short4(t0, t1, t2, t3);
    }
}

// ---------------------------------------------------------------------------
// Fused gather + L1-score + softmax + weighted-sum + blend (round-4, passing).
// ---------------------------------------------------------------------------
__global__ __launch_bounds__(256) void fuse_kernel(
    const float* __restrict__ x_loc, const int* __restrict__ indices,
    const short* __restrict__ S16, const float* __restrict__ lamda1,
    const float* __restrict__ lamda2, float* __restrict__ out)
{
    const int c = blockIdx.x;
    const int b = blockIdx.y;

    __shared__ float xs[Ln];
    __shared__ int   idx[Ln];
    __shared__ float red[4][DCP];
    __shared__ short wbf[DCP];
    __shared__ float ob[Ln];

    const int t = threadIdx.x;
    const float* xp = x_loc + ((long)b * Cn + c) * Ln;
    const int*   ip = indices + (long)b * Ln;
    ((float2*)xs)[t] = ((const float2*)xp)[t];
    ((int2*)idx)[t]  = ((const int2*)ip)[t];
    __syncthreads();

    const short* Sc = S16 + (long)c * INTRA * DCP;
    const int lane = t & 63;
    const int w    = t >> 6;
    const int r    = lane >> 4;
    const int dg   = lane & 15;

    float s0 = 0.f, s1 = 0.f, s2 = 0.f, s3 = 0.f;
    #pragma unroll 4
    for (int i = 0; i < 32; ++i) {
        const int lbase = w * 128 + i * 4;
        const int row   = idx[lbase + r];
        short4 g = *(const short4*)(Sc + (long)row * DCP + dg * 4);
        const float x = xs[lbase + r];
        s0 += fabsf(x - f_of_bf16(g.x));
        s1 += fabsf(x - f_of_bf16(g.y));
        s2 += fabsf(x - f_of_bf16(g.z));
        s3 += fabsf(x - f_of_bf16(g.w));
    }
    s0 += __shfl_xor(s0, 16); s0 += __shfl_xor(s0, 32);
    s1 += __shfl_xor(s1, 16); s1 += __shfl_xor(s1, 32);
    s2 += __shfl_xor(s2, 16); s2 += __shfl_xor(s2, 32);
    s3 += __shfl_xor(s3, 16); s3 += __shfl_xor(s3, 32);
    if (lane < 16) {
        red[w][dg * 4 + 0] = s0;
        red[w][dg * 4 + 1] = s1;
        red[w][dg * 4 + 2] = s2;
        red[w][dg * 4 + 3] = s3;
    }
    __syncthreads();

    if (t < DCP) {
        float sc = red[0][t] + red[1][t] + red[2][t] + red[3][t];
        sc = -sc * (SCALEF * 0.044194173824159216f);
        float m = sc;
        #pragma unroll
        for (int o = 32; o > 0; o >>= 1) m = fmaxf(m, __shfl_xor(m, o));
        float e = __expf(sc - m);
        float ssum = e;
        #pragma unroll
        for (int o = 32; o > 0; o >>= 1) ssum += __shfl_xor(ssum, o);
        wbf[t] = bf16_of(e / ssum);
    }
    __syncthreads();

    const int quad = lane >> 4;
    const int ln16 = lane & 15;
    short8 bw0 = *(const short8*)&wbf[quad * 8];
    short8 bw1 = *(const short8*)&wbf[32 + quad * 8];

    #pragma unroll
    for (int mt = 0; mt < 8; ++mt) {
        const int mrow = w * 128 + mt * 16 + ln16;
        const short* rp = Sc + (long)idx[mrow] * DCP;
        short8 a0 = *(const short8*)(rp + quad * 8);
        short8 a1 = *(const short8*)(rp + 32 + quad * 8);
        floatx4 acc = {};
        acc = __builtin_amdgcn_mfma_f32_16x16x32_bf16(a0, bw0, acc, 0, 0, 0);
        acc = __builtin_amdgcn_mfma_f32_16x16x32_bf16(a1, bw1, acc, 0, 0, 0);
        if (ln16 == 0) {
            const int l0 = w * 128 + mt * 16 + quad * 4;
            ob[l0 + 0] = acc[0];
            ob[l0 + 1] = acc[1];
            ob[l0 + 2] = acc[2];
            ob[l0 + 3] = acc[3];
        }
    }
    __syncthreads();

    const float lam1 = 1.f / (1.f + __expf(-lamda1[c]));
    #pragma unroll
    for (int j = 0; j < 2; ++j) {
        const int l = t + j * 256;
        const float lam = lam1 * (1.f / (1.f + __expf(-lamda2[l])));
        out[((long)b * Cn + c) * Ln + l] = ob[l] * lam + xs[l] * (1.f - lam);
    }
}

// ---------------------------------------------------------------------------
// Launch: 4 dispatches (prep_weights eliminated).
// ---------------------------------------------------------------------------
extern "C" void kernel_launch(void* const* d_in, const int* in_sizes, int n_in,
                              void* d_out, int out_size, void* d_ws, size_t ws_size,
                              hipStream_t stream)
{
    const float* x_loc   = (const float*)d_in[0];
    const int*   indices = (const int*)d_in[1];
    const float* map_raw = (const float*)d_in[2];
    const float* cW1     = (const float*)d_in[3];
    const float* cb1     = (const float*)d_in[4];
    const float* cW2     = (const float*)d_in[5];
    const float* cb2     = (const float*)d_in[6];
    const float* dW1     = (const float*)d_in[7];
    const float* db1     = (const float*)d_in[8];
    const float* dW2     = (const float*)d_in[9];
    const float* db2     = (const float*)d_in[10];
    const float* lamda1  = (const float*)d_in[11];
    const float* lamda2  = (const float*)d_in[12];
    float* out = (float*)d_out;

    short* wsS = (short*)d_ws;
    short* M1T = wsS;                 // 32*64*1024 = 2097152 bf16
    short* HT  = M1T + 2097152;       // 32*64*512  = 1048576
    short* S16 = HT + 1048576;        // 32*1024*64 = 2097152

    compress_fused<<<dim3(INTRA / 64, Cn), 256, 0, stream>>>(
        map_raw, cW1, cb1, cW2, cb2, M1T);

    gemm_dn1<<<dim3(DDE / 32, Cn), 256, 0, stream>>>(
        dW1, M1T, db1, HT);

    gemm_dn2<<<dim3(INTRA / 64, Cn), 256, 0, stream>>>(
        HT, dW2, db2, S16);

    fuse_kernel<<<dim3(Cn, Bn), 256, 0, stream>>>(
        x_loc, indices, S16, lamda1, lamda2, out);
}